// Round 6
// baseline (422.192 us; speedup 1.0000x reference)
//
#include <hip/hip_runtime.h>
#include <cstdint>
#include <cstddef>

#define BATCH 64
#define CH 3
#define HH 256
#define WW 256
#define NBINS 256
#define NPB (CH*HH*WW)         /* 196608 elements per batch item */
#define QPX (NPB/4)            /* 49152 pixels per quarter-batch-item */
#define NHB 256                /* hist-role blocks (scheduled first) */
#define NZ (BATCH*CH)          /* 192 channel-images */
#define NBANDS 8               /* 32-row bands per image */
#define NCB (NZ*NBANDS)        /* 1536 conv blocks */

__device__ __forceinline__ float block_reduce_256(float v, float* buf4) {
    #pragma unroll
    for (int o = 32; o > 0; o >>= 1) v += __shfl_down(v, o, 64);
    __syncthreads();
    int lane = threadIdx.x & 63;
    int wid  = threadIdx.x >> 6;
    if (lane == 0) buf4[wid] = v;
    __syncthreads();
    return buf4[0] + buf4[1] + buf4[2] + buf4[3];
}

__device__ __forceinline__ float block_reduce_1024(float v, float* buf16) {
    #pragma unroll
    for (int o = 32; o > 0; o >>= 1) v += __shfl_down(v, o, 64);
    __syncthreads();
    int lane = threadIdx.x & 63;
    int wid  = threadIdx.x >> 6;
    if (lane == 0) buf16[wid] = v;
    __syncthreads();
    float s = 0.0f;
    #pragma unroll
    for (int i = 0; i < 16; i++) s += buf16[i];
    return s;
}

// Heterogeneous mega-kernel.
//   bids [0,256):     hist role — u4-packed 256x256 LDS histogram partial
//                     (quarter batch item each) + per-wave MSE partials.
//   bids [256,1792):  conv role — full-row streaming bands. One block per
//                     (z, 32-row band); 256 threads = one full 256-col row.
//                     Each wave privately stages its 64+10-col segment of
//                     the current+next input row in LDS (no cross-wave
//                     sync, no bank conflicts), streams 42 rows through an
//                     11-deep register ring of v-conv accumulators (fixed
//                     weight per slot, shift-by-one keeps indices static).
//                     Eliminates strip overlap and the tile two-phase LDS
//                     pipeline entirely.
__global__ __launch_bounds__(256, 5) void mega_kernel(
    const float* __restrict__ x, const float* __restrict__ y,
    const float* __restrict__ win,
    float* __restrict__ ssim_partials,
    unsigned int* __restrict__ u4hist, float* __restrict__ mse_part)
{
    __shared__ __align__(16) unsigned char smem[32768];
    const int bid = blockIdx.x;
    const int tid = threadIdx.x;

    if (bid < NHB) {
        // ================= hist role =================
        unsigned int* h32 = (unsigned int*)smem;   // 8192 words, 8 u4 bins each
        uint4* h128 = (uint4*)h32;
        #pragma unroll
        for (int i = 0; i < 8; i++) h128[tid + i * 256] = make_uint4(0, 0, 0, 0);
        __syncthreads();

        const int b = bid >> 2, e = bid & 3;
        const float4* x4 = (const float4*)x + (size_t)b * (NPB/4) + (size_t)e * (QPX/4);
        const float4* y4 = (const float4*)y + (size_t)b * (NPB/4) + (size_t)e * (QPX/4);
        float mse_s = 0.0f;
        for (int i = 0; i < 48; i++) {
            float4 xv = x4[tid + i * 256];
            float4 yv = y4[tid + i * 256];
            float xs[4] = {xv.x, xv.y, xv.z, xv.w};
            float ys[4] = {yv.x, yv.y, yv.z, yv.w};
            #pragma unroll
            for (int q = 0; q < 4; q++) {
                float xc = xs[q], yc = ys[q];
                float d = xc - yc;
                mse_s += d * d;
                int ix = (int)(((xc + 1.0f) * 0.5f) * 256.0f);
                int iy = (int)(((yc + 1.0f) * 0.5f) * 256.0f);
                ix = min(max(ix, 0), 255);
                iy = min(max(iy, 0), 255);
                int key = ix * NBINS + iy;
                atomicAdd(&h32[key >> 3], 1u << (4 * (key & 7)));
            }
        }
        #pragma unroll
        for (int o = 32; o > 0; o >>= 1) mse_s += __shfl_down(mse_s, o, 64);
        if ((tid & 63) == 0) mse_part[bid * 4 + (tid >> 6)] = mse_s;
        __syncthreads();

        #pragma unroll
        for (int k = 0; k < 32; k++)
            u4hist[(size_t)bid * 8192 + tid + k * 256] = h32[tid + k * 256];
        return;
    }

    // ================= conv role =================
    // per-wave LDS: [wave][parity][img][80] floats = 4*2*2*80*4 = 5120 B
    float* wbuf = (float*)smem;
    float* rbuf = (float*)(smem + 5120);

    const int cb = bid - NHB;
    const int z = cb >> 3, band = cb & 7;      // z = b*3 + c
    const int w = tid >> 6, l = tid & 63;
    float* wb = wbuf + w * 320;                // this wave's 320 floats

    const float* xi = x + (size_t)z * (HH * WW);
    const float* yi = y + (size_t)z * (HH * WW);

    // normalized 1-D gaussian: g[k] = win[5][k] / sqrt(win[5][5])
    float gw[11];
    {
        float gs = sqrtf(win[60]);
        #pragma unroll
        for (int k = 0; k < 11; k++) gw[k] = win[55 + k] / gs;
    }

    const int r0g = band * 32 - 5;     // global row of staged row r=0
    const int gc  = tid - 5;           // lane's staging col (may be <0)
    const int gc2 = gc + 64;           // second staging col (l<10 only)
    const bool okc  = (gc >= 0);       // gc <= 250 always
    const bool okc2 = (gc2 < WW);      // gc2 >= 59 always

    // 11-slot register ring: slot j <-> out-row (r-10+j), fixed weight g[10-j]
    float aX[11], aY[11], aU[11], aV[11];
    #pragma unroll
    for (int j = 0; j < 11; j++) { aX[j]=0.0f; aY[j]=0.0f; aU[j]=0.0f; aV[j]=0.0f; }

    // stage input row 0 -> parity 0
    {
        int gr = r0g;
        bool okr = (gr >= 0) && (gr < HH);
        const float* xr = xi + gr * WW;
        const float* yr = yi + gr * WW;
        float xv = (okr && okc) ? xr[gc] : 0.0f;
        float yv = (okr && okc) ? yr[gc] : 0.0f;
        wb[l]      = xv;
        wb[80 + l] = yv;
        if (l < 10) {
            float xv2 = (okr && okc2) ? xr[gc2] : 0.0f;
            float yv2 = (okr && okc2) ? yr[gc2] : 0.0f;
            wb[l + 64]      = xv2;
            wb[80 + l + 64] = yv2;
        }
    }

    float ssim_s = 0.0f;
    const float C1v = 1e-4f, C2v = 9e-4f;
    #pragma unroll 1
    for (int r = 0; r < 42; ++r) {
        const int p = r & 1;
        float* cur = wb + p * 160;
        // stage row r+1 into the other parity (same wave; lgkmcnt orders it)
        if (r < 41) {
            int gr = r0g + r + 1;
            bool okr = (gr >= 0) && (gr < HH);
            const float* xr = xi + gr * WW;
            const float* yr = yi + gr * WW;
            float xv = (okr && okc) ? xr[gc] : 0.0f;
            float yv = (okr && okc) ? yr[gc] : 0.0f;
            float* nxt = wb + (p ^ 1) * 160;
            nxt[l]      = xv;
            nxt[80 + l] = yv;
            if (l < 10) {
                float xv2 = (okr && okc2) ? xr[gc2] : 0.0f;
                float yv2 = (okr && okc2) ? yr[gc2] : 0.0f;
                nxt[l + 64]      = xv2;
                nxt[80 + l + 64] = yv2;
            }
        }
        // 11-tap horizontal conv for 4 fields (x, y, x^2+y^2, x*y)
        float hx = 0.0f, hy = 0.0f, hu = 0.0f, hv = 0.0f;
        #pragma unroll
        for (int k = 0; k < 11; ++k) {
            float a  = cur[l + k];
            float b2 = cur[80 + l + k];
            float wk = gw[k];
            hx = fmaf(wk, a, hx);
            hy = fmaf(wk, b2, hy);
            float uu = fmaf(b2, b2, a * a);
            hu = fmaf(wk, uu, hu);
            float vv = a * b2;
            hv = fmaf(wk, vv, hv);
        }
        // ring update: slot j += g[10-j] * h  (all indices static)
        #pragma unroll
        for (int j = 0; j < 11; ++j) {
            float wj = gw[10 - j];
            aX[j] = fmaf(wj, hx, aX[j]);
            aY[j] = fmaf(wj, hy, aY[j]);
            aU[j] = fmaf(wj, hu, aU[j]);
            aV[j] = fmaf(wj, hv, aV[j]);
        }
        // slot 0 completes out-row r-10
        if (r >= 10) {
            float m1 = aX[0], m2 = aY[0];
            float m1s = m1 * m1, m2s = m2 * m2, m12 = m1 * m2;
            float ssum = aU[0] - m1s - m2s;     // s1 + s2
            float s12  = aV[0] - m12;
            float num = (2.0f * m12 + C1v) * (2.0f * s12 + C2v);
            float den = (m1s + m2s + C1v) * (ssum + C2v);
            ssim_s += __fdividef(num, den);
        }
        // shift ring (static indices)
        #pragma unroll
        for (int j = 0; j < 10; ++j) {
            aX[j] = aX[j+1]; aY[j] = aY[j+1]; aU[j] = aU[j+1]; aV[j] = aV[j+1];
        }
        aX[10] = 0.0f; aY[10] = 0.0f; aU[10] = 0.0f; aV[10] = 0.0f;
    }

    float ssim_b = block_reduce_256(ssim_s, rbuf);
    if (tid == 0)
        ssim_partials[(size_t)z * NBANDS + band] = ssim_b;
}

// Fused merge+finalize: 64 blocks (one per batch item) x 1024 threads.
// Loop the 4 ix-slices; SWAR-merge the 4 u4 partials per slice (4*15=60<255,
// carry-safe); Hxy & Hx terms local; column partials accumulated in LDS per
// wave (fixed-lane ownership, no atomics); then Hy, SSIM, MSE, outputs.
__global__ __launch_bounds__(1024) void merge_finalize_kernel(
    const unsigned int* __restrict__ u4hist,
    const float* __restrict__ mse_part, const float* __restrict__ ssim_partials,
    float* __restrict__ out)
{
    __shared__ unsigned int colw[16][256];   // 16 KB per-wave column partials
    __shared__ float rbuf[16];
    const int b = blockIdx.x, t = threadIdx.x;
    const int w = t >> 6, l = t & 63;
    const float invN = 1.0f / (float)NPB;

    #pragma unroll
    for (int i = 0; i < 4; i++) ((unsigned int*)colw)[t + i * 1024] = 0;
    __syncthreads();

    float sxy = 0.0f, sx = 0.0f;
    for (int s = 0; s < 4; s++) {
        unsigned int s0a = 0, s1a = 0, s0b = 0, s1b = 0;
        #pragma unroll
        for (int p = 0; p < 4; p++) {
            const uint2* src = (const uint2*)(u4hist + (size_t)(b * 4 + p) * 8192 + s * 2048);
            uint2 v = src[t];
            s0a += v.x & 0x0F0F0F0Fu;  s1a += (v.x >> 4) & 0x0F0F0F0Fu;
            s0b += v.y & 0x0F0F0F0Fu;  s1b += (v.y >> 4) & 0x0F0F0F0Fu;
        }
        unsigned int cnt[16];
        #pragma unroll
        for (int m = 0; m < 4; m++) {
            cnt[2*m]         = (s0a >> (8*m)) & 255u;
            cnt[2*m + 1]     = (s1a >> (8*m)) & 255u;
            cnt[8 + 2*m]     = (s0b >> (8*m)) & 255u;
            cnt[8 + 2*m + 1] = (s1b >> (8*m)) & 255u;
        }

        unsigned int rowc = 0;
        #pragma unroll
        for (int k = 0; k < 16; k++) {
            unsigned int v = cnt[k];
            rowc += v;
            if (v) {
                float jp = (float)v * invN;
                sxy += jp * __log2f(jp);
            }
        }
        #pragma unroll
        for (int o = 8; o > 0; o >>= 1) rowc += __shfl_xor((int)rowc, o, 16);
        if ((t & 15) == 0 && rowc) {
            float px = (float)rowc * invN;
            sx += px * __log2f(px);
        }

        #pragma unroll
        for (int k = 0; k < 16; k++) {
            cnt[k] += __shfl_xor((int)cnt[k], 16, 64);
            cnt[k] += __shfl_xor((int)cnt[k], 32, 64);
        }
        if (l < 16) {
            #pragma unroll
            for (int k = 0; k < 16; k++) colw[w][16 * l + k] += cnt[k];
        }
    }

    float sxy_blk = block_reduce_1024(sxy, rbuf);   // syncs order colw writes
    float sx_blk  = block_reduce_1024(sx, rbuf);

    float ey = 0.0f;
    if (t < 256) {
        unsigned int pc = 0;
        #pragma unroll
        for (int ww = 0; ww < 16; ww++) pc += colw[ww][t];
        if (pc) {
            float py = (float)pc * invN;
            ey = -py * __log2f(py);
        }
    }
    float hy = block_reduce_1024(ey, rbuf);
    float ssim_total = block_reduce_1024(
        (t < 24) ? ssim_partials[(size_t)b * 24 + t] : 0.0f, rbuf);
    float mse_all = block_reduce_1024(
        (t < 16) ? mse_part[b * 16 + t] : 0.0f, rbuf);

    if (t == 0) {
        float hxy = -sxy_blk;
        float hx  = -sx_blk;
        float mi = hx + hy - hxy;
        float norm = fminf(hx, hy);
        float m = (norm > 0.0f) ? (mi / norm) : 0.0f;
        m = fminf(fmaxf(m, 0.0f), 1.0f);
        out[b * 3 + 0] = m;
        out[b * 3 + 1] = ssim_total * invN;
        double mse = (double)mse_all * (1.0 / (4.0 * (double)NPB));
        out[b * 3 + 2] = (mse == 0.0) ? 2.5f : (float)(-10.0 * log10(mse) / 40.0);
    }
}

extern "C" void kernel_launch(void* const* d_in, const int* in_sizes, int n_in,
                              void* d_out, int out_size, void* d_ws, size_t ws_size,
                              hipStream_t stream) {
    const float* x   = (const float*)d_in[0];
    const float* y   = (const float*)d_in[1];
    const float* win = (const float*)d_in[2];
    float* out = (float*)d_out;

    // ws layout (everything fully written before read; no memset, no fences):
    //   u4hist:        256*8192 u32   8 MB
    //   mse_part:      1024 f32
    //   ssim_partials: 1536 f32
    char* p = (char*)d_ws;
    unsigned int* u4hist = (unsigned int*)p;
    size_t off = (size_t)NHB * 8192 * sizeof(unsigned int);
    float* mse_part = (float*)(p + off);        off += (size_t)NHB * 4 * sizeof(float);
    float* ssim_partials = (float*)(p + off);

    mega_kernel<<<dim3(NHB + NCB), dim3(256), 0, stream>>>(
        x, y, win, ssim_partials, u4hist, mse_part);
    merge_finalize_kernel<<<dim3(BATCH), dim3(1024), 0, stream>>>(
        u4hist, mse_part, ssim_partials, out);
}

// Round 7
// 216.066 us; speedup vs baseline: 1.9540x; 1.9540x over previous
//
#include <hip/hip_runtime.h>
#include <cstdint>
#include <cstddef>

#define BATCH 64
#define CH 3
#define HH 256
#define WW 256
#define NBINS 256
#define NPB (CH*HH*WW)         /* 196608 elements per batch item */
#define QPX (NPB/4)            /* 49152 pixels per quarter-batch-item */
#define NHB 256                /* hist-role blocks (scheduled first) */
#define NZ (BATCH*CH)          /* 192 channel-images */
#define NBANDS 8               /* 32-row bands per image */
#define NCB (NZ*NBANDS)        /* 1536 conv blocks */

__device__ __forceinline__ float block_reduce_256(float v, float* buf4) {
    #pragma unroll
    for (int o = 32; o > 0; o >>= 1) v += __shfl_down(v, o, 64);
    __syncthreads();
    int lane = threadIdx.x & 63;
    int wid  = threadIdx.x >> 6;
    if (lane == 0) buf4[wid] = v;
    __syncthreads();
    return buf4[0] + buf4[1] + buf4[2] + buf4[3];
}

__device__ __forceinline__ float block_reduce_1024(float v, float* buf16) {
    #pragma unroll
    for (int o = 32; o > 0; o >>= 1) v += __shfl_down(v, o, 64);
    __syncthreads();
    int lane = threadIdx.x & 63;
    int wid  = threadIdx.x >> 6;
    if (lane == 0) buf16[wid] = v;
    __syncthreads();
    float s = 0.0f;
    #pragma unroll
    for (int i = 0; i < 16; i++) s += buf16[i];
    return s;
}

// Heterogeneous mega-kernel.
//   bids [0,256):     hist role — u4-packed 256x256 LDS histogram partial
//                     (quarter batch item each) + per-wave MSE partials.
//   bids [256,1792):  conv role — full-row streaming bands. One block per
//                     (z, 32-row band); 256 threads = one full 256-col row.
//                     Per-wave LDS staging (no cross-wave sync, no bank
//                     conflicts); 11-deep vertical-conv accumulator ring
//                     held in 44 NAMED scalar floats (r6's array ring
//                     spilled to scratch under the waves-per-eu clamp:
//                     WRITE_SIZE 8.6->79 MB. No launch_bounds min here).
__global__ __launch_bounds__(256) void mega_kernel(
    const float* __restrict__ x, const float* __restrict__ y,
    const float* __restrict__ win,
    float* __restrict__ ssim_partials,
    unsigned int* __restrict__ u4hist, float* __restrict__ mse_part)
{
    __shared__ __align__(16) unsigned char smem[32768];
    const int bid = blockIdx.x;
    const int tid = threadIdx.x;

    if (bid < NHB) {
        // ================= hist role =================
        unsigned int* h32 = (unsigned int*)smem;   // 8192 words, 8 u4 bins each
        uint4* h128 = (uint4*)h32;
        #pragma unroll
        for (int i = 0; i < 8; i++) h128[tid + i * 256] = make_uint4(0, 0, 0, 0);
        __syncthreads();

        const int b = bid >> 2, e = bid & 3;
        const float4* x4 = (const float4*)x + (size_t)b * (NPB/4) + (size_t)e * (QPX/4);
        const float4* y4 = (const float4*)y + (size_t)b * (NPB/4) + (size_t)e * (QPX/4);
        float mse_s = 0.0f;
        for (int i = 0; i < 48; i++) {
            float4 xv = x4[tid + i * 256];
            float4 yv = y4[tid + i * 256];
            float xs[4] = {xv.x, xv.y, xv.z, xv.w};
            float ys[4] = {yv.x, yv.y, yv.z, yv.w};
            #pragma unroll
            for (int q = 0; q < 4; q++) {
                float xc = xs[q], yc = ys[q];
                float d = xc - yc;
                mse_s += d * d;
                int ix = (int)(((xc + 1.0f) * 0.5f) * 256.0f);
                int iy = (int)(((yc + 1.0f) * 0.5f) * 256.0f);
                ix = min(max(ix, 0), 255);
                iy = min(max(iy, 0), 255);
                int key = ix * NBINS + iy;
                atomicAdd(&h32[key >> 3], 1u << (4 * (key & 7)));
            }
        }
        #pragma unroll
        for (int o = 32; o > 0; o >>= 1) mse_s += __shfl_down(mse_s, o, 64);
        if ((tid & 63) == 0) mse_part[bid * 4 + (tid >> 6)] = mse_s;
        __syncthreads();

        #pragma unroll
        for (int k = 0; k < 32; k++)
            u4hist[(size_t)bid * 8192 + tid + k * 256] = h32[tid + k * 256];
        return;
    }

    // ================= conv role =================
    // per-wave LDS: [wave][parity][img][80] floats = 4*2*2*80*4 = 5120 B
    float* wbuf = (float*)smem;
    float* rbuf = (float*)(smem + 5120);

    const int cb = bid - NHB;
    const int z = cb >> 3, band = cb & 7;      // z = b*3 + c
    const int w = tid >> 6, l = tid & 63;
    float* wb = wbuf + w * 320;                // this wave's 320 floats

    const float* xi = x + (size_t)z * (HH * WW);
    const float* yi = y + (size_t)z * (HH * WW);

    // normalized 1-D gaussian: g[k] = win[5][k] / sqrt(win[5][5])
    float g0, g1, g2, g3, g4, g5, g6, g7, g8, g9, g10;
    {
        float gs = sqrtf(win[60]);
        g0 = win[55] / gs;  g1 = win[56] / gs;  g2 = win[57] / gs;
        g3 = win[58] / gs;  g4 = win[59] / gs;  g5 = win[60] / gs;
        g6 = win[61] / gs;  g7 = win[62] / gs;  g8 = win[63] / gs;
        g9 = win[64] / gs;  g10 = win[65] / gs;
    }

    const int r0g = band * 32 - 5;     // global row of staged row r=0
    const int gc  = tid - 5;           // lane's staging col (may be <0)
    const int gc2 = gc + 64;           // second staging col (l<10 only)
    const bool okc  = (gc >= 0);       // gc <= 250 always
    const bool okc2 = (gc2 < WW);      // gc2 >= 59 always

    // 11-slot ring, fully scalarized: slot j <-> out-row (r-10+j),
    // fixed weight g[10-j].
#define RING_DECL(F) float F##0=0.f,F##1=0.f,F##2=0.f,F##3=0.f,F##4=0.f, \
    F##5=0.f,F##6=0.f,F##7=0.f,F##8=0.f,F##9=0.f,F##10=0.f
    RING_DECL(aX); RING_DECL(aY); RING_DECL(aU); RING_DECL(aV);

    // stage input row 0 -> parity 0
    {
        int gr = r0g;
        bool okr = (gr >= 0) && (gr < HH);
        const float* xr = xi + gr * WW;
        const float* yr = yi + gr * WW;
        float xv = (okr && okc) ? xr[gc] : 0.0f;
        float yv = (okr && okc) ? yr[gc] : 0.0f;
        wb[l]      = xv;
        wb[80 + l] = yv;
        if (l < 10) {
            float xv2 = (okr && okc2) ? xr[gc2] : 0.0f;
            float yv2 = (okr && okc2) ? yr[gc2] : 0.0f;
            wb[l + 64]      = xv2;
            wb[80 + l + 64] = yv2;
        }
    }

    float ssim_s = 0.0f;
    const float C1v = 1e-4f, C2v = 9e-4f;
    #pragma unroll 1
    for (int r = 0; r < 42; ++r) {
        const int p = r & 1;
        float* cur = wb + p * 160;
        // stage row r+1 into the other parity (same wave; lgkmcnt orders it)
        if (r < 41) {
            int gr = r0g + r + 1;
            bool okr = (gr >= 0) && (gr < HH);
            const float* xr = xi + gr * WW;
            const float* yr = yi + gr * WW;
            float xv = (okr && okc) ? xr[gc] : 0.0f;
            float yv = (okr && okc) ? yr[gc] : 0.0f;
            float* nxt = wb + (p ^ 1) * 160;
            nxt[l]      = xv;
            nxt[80 + l] = yv;
            if (l < 10) {
                float xv2 = (okr && okc2) ? xr[gc2] : 0.0f;
                float yv2 = (okr && okc2) ? yr[gc2] : 0.0f;
                nxt[l + 64]      = xv2;
                nxt[80 + l + 64] = yv2;
            }
        }
        // 11-tap horizontal conv for 4 fields (x, y, x^2+y^2, x*y)
        float hx = 0.0f, hy = 0.0f, hu = 0.0f, hv = 0.0f;
#define HTAP(K, GK) { \
            float a  = cur[l + K]; \
            float b2 = cur[80 + l + K]; \
            hx = fmaf(GK, a, hx); \
            hy = fmaf(GK, b2, hy); \
            float uu = fmaf(b2, b2, a * a); \
            hu = fmaf(GK, uu, hu); \
            float vv = a * b2; \
            hv = fmaf(GK, vv, hv); }
        HTAP(0, g0)  HTAP(1, g1)  HTAP(2, g2)  HTAP(3, g3)  HTAP(4, g4)
        HTAP(5, g5)  HTAP(6, g6)  HTAP(7, g7)  HTAP(8, g8)  HTAP(9, g9)
        HTAP(10, g10)
#undef HTAP
        // ring update: slot j += g[10-j] * h  (all names static)
#define RUPD(J, W) aX##J = fmaf(W, hx, aX##J); aY##J = fmaf(W, hy, aY##J); \
                   aU##J = fmaf(W, hu, aU##J); aV##J = fmaf(W, hv, aV##J);
        RUPD(0, g10) RUPD(1, g9) RUPD(2, g8) RUPD(3, g7) RUPD(4, g6)
        RUPD(5, g5)  RUPD(6, g4) RUPD(7, g3) RUPD(8, g2) RUPD(9, g1)
        RUPD(10, g0)
#undef RUPD
        // slot 0 completes out-row r-10
        if (r >= 10) {
            float m1 = aX0, m2 = aY0;
            float m1s = m1 * m1, m2s = m2 * m2, m12 = m1 * m2;
            float ssum = aU0 - m1s - m2s;       // s1 + s2
            float s12  = aV0 - m12;
            float num = (2.0f * m12 + C1v) * (2.0f * s12 + C2v);
            float den = (m1s + m2s + C1v) * (ssum + C2v);
            ssim_s += __fdividef(num, den);
        }
        // shift ring (static names)
#define RSH(A, B) aX##A = aX##B; aY##A = aY##B; aU##A = aU##B; aV##A = aV##B;
        RSH(0,1) RSH(1,2) RSH(2,3) RSH(3,4) RSH(4,5)
        RSH(5,6) RSH(6,7) RSH(7,8) RSH(8,9) RSH(9,10)
#undef RSH
        aX10 = 0.0f; aY10 = 0.0f; aU10 = 0.0f; aV10 = 0.0f;
    }

    float ssim_b = block_reduce_256(ssim_s, rbuf);
    if (tid == 0)
        ssim_partials[(size_t)z * NBANDS + band] = ssim_b;
}

// Fused merge+finalize: 64 blocks (one per batch item) x 1024 threads.
// Loop the 4 ix-slices; SWAR-merge the 4 u4 partials per slice (4*15=60<255,
// carry-safe); Hxy & Hx terms local; column partials accumulated in LDS per
// wave (fixed-lane ownership, no atomics); then Hy, SSIM, MSE, outputs.
__global__ __launch_bounds__(1024) void merge_finalize_kernel(
    const unsigned int* __restrict__ u4hist,
    const float* __restrict__ mse_part, const float* __restrict__ ssim_partials,
    float* __restrict__ out)
{
    __shared__ unsigned int colw[16][256];   // 16 KB per-wave column partials
    __shared__ float rbuf[16];
    const int b = blockIdx.x, t = threadIdx.x;
    const int w = t >> 6, l = t & 63;
    const float invN = 1.0f / (float)NPB;

    #pragma unroll
    for (int i = 0; i < 4; i++) ((unsigned int*)colw)[t + i * 1024] = 0;
    __syncthreads();

    float sxy = 0.0f, sx = 0.0f;
    for (int s = 0; s < 4; s++) {
        unsigned int s0a = 0, s1a = 0, s0b = 0, s1b = 0;
        #pragma unroll
        for (int p = 0; p < 4; p++) {
            const uint2* src = (const uint2*)(u4hist + (size_t)(b * 4 + p) * 8192 + s * 2048);
            uint2 v = src[t];
            s0a += v.x & 0x0F0F0F0Fu;  s1a += (v.x >> 4) & 0x0F0F0F0Fu;
            s0b += v.y & 0x0F0F0F0Fu;  s1b += (v.y >> 4) & 0x0F0F0F0Fu;
        }
        unsigned int cnt[16];
        #pragma unroll
        for (int m = 0; m < 4; m++) {
            cnt[2*m]         = (s0a >> (8*m)) & 255u;
            cnt[2*m + 1]     = (s1a >> (8*m)) & 255u;
            cnt[8 + 2*m]     = (s0b >> (8*m)) & 255u;
            cnt[8 + 2*m + 1] = (s1b >> (8*m)) & 255u;
        }

        unsigned int rowc = 0;
        #pragma unroll
        for (int k = 0; k < 16; k++) {
            unsigned int v = cnt[k];
            rowc += v;
            if (v) {
                float jp = (float)v * invN;
                sxy += jp * __log2f(jp);
            }
        }
        #pragma unroll
        for (int o = 8; o > 0; o >>= 1) rowc += __shfl_xor((int)rowc, o, 16);
        if ((t & 15) == 0 && rowc) {
            float px = (float)rowc * invN;
            sx += px * __log2f(px);
        }

        #pragma unroll
        for (int k = 0; k < 16; k++) {
            cnt[k] += __shfl_xor((int)cnt[k], 16, 64);
            cnt[k] += __shfl_xor((int)cnt[k], 32, 64);
        }
        if (l < 16) {
            #pragma unroll
            for (int k = 0; k < 16; k++) colw[w][16 * l + k] += cnt[k];
        }
    }

    float sxy_blk = block_reduce_1024(sxy, rbuf);   // syncs order colw writes
    float sx_blk  = block_reduce_1024(sx, rbuf);

    float ey = 0.0f;
    if (t < 256) {
        unsigned int pc = 0;
        #pragma unroll
        for (int ww = 0; ww < 16; ww++) pc += colw[ww][t];
        if (pc) {
            float py = (float)pc * invN;
            ey = -py * __log2f(py);
        }
    }
    float hy = block_reduce_1024(ey, rbuf);
    float ssim_total = block_reduce_1024(
        (t < 24) ? ssim_partials[(size_t)b * 24 + t] : 0.0f, rbuf);
    float mse_all = block_reduce_1024(
        (t < 16) ? mse_part[b * 16 + t] : 0.0f, rbuf);

    if (t == 0) {
        float hxy = -sxy_blk;
        float hx  = -sx_blk;
        float mi = hx + hy - hxy;
        float norm = fminf(hx, hy);
        float m = (norm > 0.0f) ? (mi / norm) : 0.0f;
        m = fminf(fmaxf(m, 0.0f), 1.0f);
        out[b * 3 + 0] = m;
        out[b * 3 + 1] = ssim_total * invN;
        double mse = (double)mse_all * (1.0 / (4.0 * (double)NPB));
        out[b * 3 + 2] = (mse == 0.0) ? 2.5f : (float)(-10.0 * log10(mse) / 40.0);
    }
}

extern "C" void kernel_launch(void* const* d_in, const int* in_sizes, int n_in,
                              void* d_out, int out_size, void* d_ws, size_t ws_size,
                              hipStream_t stream) {
    const float* x   = (const float*)d_in[0];
    const float* y   = (const float*)d_in[1];
    const float* win = (const float*)d_in[2];
    float* out = (float*)d_out;

    // ws layout (everything fully written before read; no memset, no fences):
    //   u4hist:        256*8192 u32   8 MB
    //   mse_part:      1024 f32
    //   ssim_partials: 1536 f32
    char* p = (char*)d_ws;
    unsigned int* u4hist = (unsigned int*)p;
    size_t off = (size_t)NHB * 8192 * sizeof(unsigned int);
    float* mse_part = (float*)(p + off);        off += (size_t)NHB * 4 * sizeof(float);
    float* ssim_partials = (float*)(p + off);

    mega_kernel<<<dim3(NHB + NCB), dim3(256), 0, stream>>>(
        x, y, win, ssim_partials, u4hist, mse_part);
    merge_finalize_kernel<<<dim3(BATCH), dim3(1024), 0, stream>>>(
        u4hist, mse_part, ssim_partials, out);
}